// Round 2
// baseline (43.357 us; speedup 1.0000x reference)
//
#include <hip/hip_runtime.h>
#include <hip/hip_bf16.h>
#include <float.h>

#define HH 4096
#define WW 4096

__global__ __launch_bounds__(256) void nms_kernel(
    const float* __restrict__ rel,
    const float* __restrict__ rep,
    const float* __restrict__ rel_thr_p,
    const float* __restrict__ rep_thr_p,
    int* __restrict__ out)
{
    const int x0 = (blockIdx.x * blockDim.x + threadIdx.x) * 4;   // first pixel of this thread
    const int y  = blockIdx.y;
    if (x0 >= WW || y >= HH) return;

    const float rel_thr = *rel_thr_p;
    const float rep_thr = *rep_thr_p;

    const float NEG = -FLT_MAX;

    float m0 = NEG, m1 = NEG, m2 = NEG, m3 = NEG;  // running 3x3 window max per output pixel
    float c0 = 0.f, c1 = 0.f, c2 = 0.f, c3 = 0.f;  // center-row values

    #pragma unroll
    for (int dy = -1; dy <= 1; ++dy) {
        const int yy = y + dy;
        if (yy < 0 || yy >= HH) continue;
        const float* row = rep + (size_t)yy * WW;
        const float4 v = *reinterpret_cast<const float4*>(row + x0);
        const float left  = (x0 > 0)       ? row[x0 - 1] : NEG;
        const float right = (x0 + 4 < WW)  ? row[x0 + 4] : NEG;
        if (dy == 0) { c0 = v.x; c1 = v.y; c2 = v.z; c3 = v.w; }
        // horizontal 3-tap max for each of the 4 pixels
        m0 = fmaxf(m0, fmaxf(fmaxf(left, v.x), v.y));
        m1 = fmaxf(m1, fmaxf(fmaxf(v.x,  v.y), v.z));
        m2 = fmaxf(m2, fmaxf(fmaxf(v.y,  v.z), v.w));
        m3 = fmaxf(m3, fmaxf(fmaxf(v.z,  v.w), right));
    }

    const float4 rl = *reinterpret_cast<const float4*>(rel + (size_t)y * WW + x0);

    int4 o;
    o.x = (c0 == m0 && c0 >= rep_thr && rl.x >= rel_thr) ? 1 : 0;
    o.y = (c1 == m1 && c1 >= rep_thr && rl.y >= rel_thr) ? 1 : 0;
    o.z = (c2 == m2 && c2 >= rep_thr && rl.z >= rel_thr) ? 1 : 0;
    o.w = (c3 == m3 && c3 >= rep_thr && rl.w >= rel_thr) ? 1 : 0;

    *reinterpret_cast<int4*>(out + (size_t)y * WW + x0) = o;
}

extern "C" void kernel_launch(void* const* d_in, const int* in_sizes, int n_in,
                              void* d_out, int out_size, void* d_ws, size_t ws_size,
                              hipStream_t stream)
{
    const float* rel       = (const float*)d_in[0];
    const float* rep       = (const float*)d_in[1];
    const float* rel_thr_p = (const float*)d_in[2];
    const float* rep_thr_p = (const float*)d_in[3];
    int* out = (int*)d_out;

    dim3 block(256, 1, 1);
    dim3 grid(WW / (256 * 4), HH, 1);   // 4 x-blocks of 1024 px, one row per grid.y
    nms_kernel<<<grid, block, 0, stream>>>(rel, rep, rel_thr_p, rep_thr_p, out);
}

// Round 3
// 35.766 us; speedup vs baseline: 1.2122x; 1.2122x over previous
//
#include <hip/hip_runtime.h>
#include <hip/hip_bf16.h>
#include <float.h>

#define HH 4096
#define WW 4096
#define RROWS 8   // output rows per thread

__global__ __launch_bounds__(256) void nms_kernel(
    const float* __restrict__ rel,
    const float* __restrict__ rep,
    const float* __restrict__ rel_thr_p,
    const float* __restrict__ rep_thr_p,
    int* __restrict__ out)
{
    const int x0    = (blockIdx.x * 256 + threadIdx.x) * 4;   // first pixel (4 px/thread in x)
    const int ybase = blockIdx.y * RROWS;
    const int lane  = threadIdx.x & 63;

    const float rel_thr = *rel_thr_p;
    const float rep_thr = *rep_thr_p;
    const float NEG = -FLT_MAX;

    // load rep row yy, return horizontal 3-tap max per pixel; center values in c
    auto loadrow = [&](int yy, float4& c) -> float4 {
        float4 h;
        if (yy < 0 || yy >= HH) {            // wave-uniform branch (yy uniform per block)
            c = make_float4(NEG, NEG, NEG, NEG);
            return make_float4(NEG, NEG, NEG, NEG);
        }
        const float* row = rep + (size_t)yy * WW;
        const float4 v = *reinterpret_cast<const float4*>(row + x0);
        float left  = __shfl_up(v.w, 1);
        if (lane == 0)  left  = (x0 > 0)      ? row[x0 - 1] : NEG;
        float right = __shfl_down(v.x, 1);
        if (lane == 63) right = (x0 + 4 < WW) ? row[x0 + 4] : NEG;
        c = v;
        h.x = fmaxf(fmaxf(left, v.x), v.y);
        h.y = fmaxf(fmaxf(v.x,  v.y), v.z);
        h.z = fmaxf(fmaxf(v.y,  v.z), v.w);
        h.w = fmaxf(fmaxf(v.z,  v.w), right);
        return h;
    };

    float4 cCur, cNext, cDump;
    float4 hmA = loadrow(ybase - 1, cDump);   // row above
    float4 hmB = loadrow(ybase,     cCur);    // current row

    #pragma unroll
    for (int i = 0; i < RROWS; ++i) {
        const int y = ybase + i;
        float4 hmC = loadrow(y + 1, cNext);   // row below

        const float4 rl = *reinterpret_cast<const float4*>(rel + (size_t)y * WW + x0);

        int4 o;
        float m;
        m   = fmaxf(fmaxf(hmA.x, hmB.x), hmC.x);
        o.x = (cCur.x == m && cCur.x >= rep_thr && rl.x >= rel_thr) ? 1 : 0;
        m   = fmaxf(fmaxf(hmA.y, hmB.y), hmC.y);
        o.y = (cCur.y == m && cCur.y >= rep_thr && rl.y >= rel_thr) ? 1 : 0;
        m   = fmaxf(fmaxf(hmA.z, hmB.z), hmC.z);
        o.z = (cCur.z == m && cCur.z >= rep_thr && rl.z >= rel_thr) ? 1 : 0;
        m   = fmaxf(fmaxf(hmA.w, hmB.w), hmC.w);
        o.w = (cCur.w == m && cCur.w >= rep_thr && rl.w >= rel_thr) ? 1 : 0;

        *reinterpret_cast<int4*>(out + (size_t)y * WW + x0) = o;

        hmA = hmB; hmB = hmC; cCur = cNext;   // roll the 3-row window down
    }
}

extern "C" void kernel_launch(void* const* d_in, const int* in_sizes, int n_in,
                              void* d_out, int out_size, void* d_ws, size_t ws_size,
                              hipStream_t stream)
{
    const float* rel       = (const float*)d_in[0];
    const float* rep       = (const float*)d_in[1];
    const float* rel_thr_p = (const float*)d_in[2];
    const float* rep_thr_p = (const float*)d_in[3];
    int* out = (int*)d_out;

    dim3 block(256, 1, 1);
    dim3 grid(WW / (256 * 4), HH / RROWS, 1);   // 1024-px-wide, 8-row-tall tiles
    nms_kernel<<<grid, block, 0, stream>>>(rel, rep, rel_thr_p, rep_thr_p, out);
}

// Round 4
// 34.736 us; speedup vs baseline: 1.2482x; 1.0297x over previous
//
#include <hip/hip_runtime.h>
#include <hip/hip_bf16.h>
#include <float.h>

#define HH 4096
#define WW 4096
#define RROWS 8   // output rows per thread

__global__ __launch_bounds__(256) void nms_kernel(
    const float* __restrict__ rel,
    const float* __restrict__ rep,
    const float* __restrict__ rel_thr_p,
    const float* __restrict__ rep_thr_p,
    int* __restrict__ out)
{
    // XCD-chunked bijective swizzle (nwg = 2048, %8 == 0), then column-major
    // tile walk: each XCD chunk covers 256 vertically-consecutive tiles of one
    // x-column, so the 2 halo rows per tile are same-XCD L2 hits.
    const int bid  = blockIdx.x;          // 0..2047
    const int xcd  = bid & 7;
    const int wgid = xcd * 256 + (bid >> 3);
    const int bx   = wgid >> 9;           // / 512  -> 0..3
    const int by   = wgid & 511;          // % 512

    const int x0    = (bx * 256 + threadIdx.x) * 4;   // 4 px/thread in x
    const int ybase = by * RROWS;
    const int lane  = threadIdx.x & 63;

    const float rel_thr = *rel_thr_p;
    const float rep_thr = *rep_thr_p;
    const float NEG = -FLT_MAX;

    // load rep row yy, return horizontal 3-tap max per pixel; center values in c
    auto loadrow = [&](int yy, float4& c) -> float4 {
        float4 h;
        if (yy < 0 || yy >= HH) {            // wave-uniform (yy uniform per block)
            c = make_float4(NEG, NEG, NEG, NEG);
            return make_float4(NEG, NEG, NEG, NEG);
        }
        const float* row = rep + (size_t)yy * WW;
        const float4 v = *reinterpret_cast<const float4*>(row + x0);
        float left  = __shfl_up(v.w, 1);
        if (lane == 0)  left  = (x0 > 0)      ? row[x0 - 1] : NEG;
        float right = __shfl_down(v.x, 1);
        if (lane == 63) right = (x0 + 4 < WW) ? row[x0 + 4] : NEG;
        c = v;
        h.x = fmaxf(fmaxf(left, v.x), v.y);
        h.y = fmaxf(fmaxf(v.x,  v.y), v.z);
        h.z = fmaxf(fmaxf(v.y,  v.z), v.w);
        h.w = fmaxf(fmaxf(v.z,  v.w), right);
        return h;
    };

    float4 cCur, cNext, cDump;
    float4 hmA = loadrow(ybase - 1, cDump);   // row above
    float4 hmB = loadrow(ybase,     cCur);    // current row

    #pragma unroll
    for (int i = 0; i < RROWS; ++i) {
        const int y = ybase + i;
        float4 hmC = loadrow(y + 1, cNext);   // row below

        // candidate = (rep == 3x3 max) && (rep >= rep_thr)  -- ~3% of pixels
        float m0 = fmaxf(fmaxf(hmA.x, hmB.x), hmC.x);
        float m1 = fmaxf(fmaxf(hmA.y, hmB.y), hmC.y);
        float m2 = fmaxf(fmaxf(hmA.z, hmB.z), hmC.z);
        float m3 = fmaxf(fmaxf(hmA.w, hmB.w), hmC.w);
        const bool k0 = (cCur.x == m0) && (cCur.x >= rep_thr);
        const bool k1 = (cCur.y == m1) && (cCur.y >= rep_thr);
        const bool k2 = (cCur.z == m2) && (cCur.z >= rep_thr);
        const bool k3 = (cCur.w == m3) && (cCur.w >= rep_thr);

        // predicated rel load: lanes with no candidate issue no address ->
        // only ~40% of rel cache lines are fetched.
        float4 rl = make_float4(0.f, 0.f, 0.f, 0.f);
        if (k0 | k1 | k2 | k3)
            rl = *reinterpret_cast<const float4*>(rel + (size_t)y * WW + x0);

        int4 o;
        o.x = (k0 && rl.x >= rel_thr) ? 1 : 0;
        o.y = (k1 && rl.y >= rel_thr) ? 1 : 0;
        o.z = (k2 && rl.z >= rel_thr) ? 1 : 0;
        o.w = (k3 && rl.w >= rel_thr) ? 1 : 0;

        *reinterpret_cast<int4*>(out + (size_t)y * WW + x0) = o;

        hmA = hmB; hmB = hmC; cCur = cNext;   // roll the 3-row window down
    }
}

extern "C" void kernel_launch(void* const* d_in, const int* in_sizes, int n_in,
                              void* d_out, int out_size, void* d_ws, size_t ws_size,
                              hipStream_t stream)
{
    const float* rel       = (const float*)d_in[0];
    const float* rep       = (const float*)d_in[1];
    const float* rel_thr_p = (const float*)d_in[2];
    const float* rep_thr_p = (const float*)d_in[3];
    int* out = (int*)d_out;

    dim3 block(256, 1, 1);
    dim3 grid(2048, 1, 1);   // 4 x-tiles * 512 y-tiles, swizzled in-kernel
    nms_kernel<<<grid, block, 0, stream>>>(rel, rep, rel_thr_p, rep_thr_p, out);
}